// Round 12
// baseline (245.751 us; speedup 1.0000x reference)
//
#include <hip/hip_runtime.h>
#include <stdint.h>

typedef unsigned short u16;
typedef unsigned int u32;
typedef __attribute__((ext_vector_type(2))) float f32x2;
typedef __attribute__((ext_vector_type(4))) float f32x4;
typedef __attribute__((ext_vector_type(4))) u32 u32x4;
typedef __attribute__((ext_vector_type(2))) u32 u32x2;
typedef __attribute__((ext_vector_type(8))) short bf16x8;

#define NKEYS 65536
#define DIM 1024
#define NCLS 103
#define NCAND 64
#define SROW 40   // padded LDS row stride in u16 (80 B = 5 bank-quads, coprime with 8)

__device__ __forceinline__ u16 f2bf(float x) {
  u32 u = __float_as_uint(x);
  u = u + 0x7FFFu + ((u >> 16) & 1u);
  return (u16)(u >> 16);
}
// packed f32x2 -> bf16x2; used identically on A and B packing so any intra-pair
// k-permutation cancels in the dot product.
__device__ __forceinline__ u32 cvtpk(float lo, float hi) {
  u32 d;
  asm("v_cvt_pk_bf16_f32 %0, %1, %2" : "=v"(d) : "v"(lo), "v"(hi));
  return d;
}

// ---------------- K1: q = relu(query @ Wenc^T + benc), qb = bf16(q)
// Full-K (no split), fused epilogue. Tile 32m x 64n, grid (16,8)=128 blocks,
// 256 thr, 2x4 acc/thread, K-chunks of 32, double-buffered LDS.
__global__ __launch_bounds__(256) void gemm1f(
    const float* __restrict__ A, const float* __restrict__ B,
    const float* __restrict__ bias, float* __restrict__ outf,
    u16* __restrict__ outb)
{
  __shared__ float sAT[2][32][34];
  __shared__ float sBT[2][32][66];
  const int tid = threadIdx.x;
  const int n0 = blockIdx.x * 64;
  const int m0 = blockIdx.y * 32;
  const int tx = tid & 15, ty = tid >> 4;
  const int am = tid & 31, ak = (tid >> 5) * 4;
  const int bn = tid & 63, bk = (tid >> 6) * 8;
  const float* ag = A + (size_t)(m0 + am) * DIM + ak;
  const float* bg = B + (size_t)(n0 + bn) * DIM + bk;
  float acc[2][4] = {};

  f32x4 av = *(const f32x4*)ag;
  f32x4 bv0 = *(const f32x4*)bg;
  f32x4 bv1 = *(const f32x4*)(bg + 4);
#pragma unroll
  for (int i = 0; i < 4; ++i) {
    sAT[0][ak + i][am] = av[i];
    sBT[0][bk + i][bn] = bv0[i];
    sBT[0][bk + 4 + i][bn] = bv1[i];
  }
  __syncthreads();

  for (int kb = 0; kb < 32; ++kb) {
    const int cur = kb & 1;
    if (kb + 1 < 32) {
      av  = *(const f32x4*)(ag + (kb + 1) * 32);
      bv0 = *(const f32x4*)(bg + (kb + 1) * 32);
      bv1 = *(const f32x4*)(bg + (kb + 1) * 32 + 4);
    }
#pragma unroll
    for (int kk = 0; kk < 32; ++kk) {
      const f32x2 a2 = *(const f32x2*)&sAT[cur][kk][ty * 2];
      const f32x4 b4 = *(const f32x4*)&sBT[cur][kk][tx * 4];
#pragma unroll
      for (int i = 0; i < 2; ++i)
#pragma unroll
        for (int j = 0; j < 4; ++j) acc[i][j] += a2[i] * b4[j];
    }
    if (kb + 1 < 32) {
#pragma unroll
      for (int i = 0; i < 4; ++i) {
        sAT[cur ^ 1][ak + i][am] = av[i];
        sBT[cur ^ 1][bk + i][bn] = bv0[i];
        sBT[cur ^ 1][bk + 4 + i][bn] = bv1[i];
      }
    }
    __syncthreads();
  }

#pragma unroll
  for (int i = 0; i < 2; ++i) {
    const int m = m0 + ty * 2 + i;
    const int n = n0 + tx * 4;
    f32x4 s = {acc[i][0], acc[i][1], acc[i][2], acc[i][3]};
    s += *(const f32x4*)(bias + n);
#pragma unroll
    for (int e = 0; e < 4; ++e) s[e] = fmaxf(s[e], 0.f);
    *(f32x4*)(outf + (size_t)m * DIM + n) = s;
    u32x2 h = {cvtpk(s[0], s[1]), cvtpk(s[2], s[3])};
    *(u32x2*)(outb + (size_t)m * DIM + n) = h;
  }
}

// ---------------- K2: sim GEMM (R4-proven structure, BN=128, 512 blocks) plus a
// per-block gemm2 tail: after the sim epilogue each block computes one 16x32
// tile of qt = relu(q @ Wd^T + bd) (512-tile bijection, LDS reused via union).
union SimSmem {
  struct { u16 sA[2][256 * SROW]; u16 sB[2][128 * SROW]; float snorm[128]; } s; // ~62 KB
  struct { float sA2[2][32][20]; float sB2[2][32][36]; } g;                     // ~14 KB
};

__global__ __launch_bounds__(512) void simgemm2(
    const float* __restrict__ keys, const u16* __restrict__ qb,
    const float* __restrict__ q, const float* __restrict__ Wd,
    const float* __restrict__ bd, u16* __restrict__ sim,
    float* __restrict__ qt)
{
  __shared__ SimSmem sm;
  u16 (&lsA)[2][256 * SROW] = sm.s.sA;
  u16 (&lsB)[2][128 * SROW] = sm.s.sB;
  const int tid = threadIdx.x;
  const int n0 = blockIdx.x * 128;

  const int a_r = tid >> 1;
  const int a_h = (tid & 1) * 16;
  const u16* agp = qb + (size_t)a_r * DIM + a_h;
  const int a_ws = a_r * SROW + a_h;

  const int b_r = tid >> 2;
  const int b_q = (tid & 3) * 8;
  const float* bgp = keys + (size_t)(n0 + b_r) * DIM + b_q;
  const int b_ws = b_r * SROW + b_q;

  const int lane = tid & 63, wave = tid >> 6;
  const int wm = (wave >> 1) * 64;
  const int wn = (wave & 1) * 64;
  const int lr = lane & 15;
  const int lk = (lane >> 4) * 8;
  const int l4 = (lane >> 4) * 4;

  float nrm = 0.f;
  f32x4 acc[4][4];
#pragma unroll
  for (int i = 0; i < 4; ++i)
#pragma unroll
    for (int j = 0; j < 4; ++j) acc[i][j] = (f32x4){0.f, 0.f, 0.f, 0.f};

  f32x4 b00, b01, b10, b11, b20, b21, b30, b31;
  u32x4 a00, a01, a10, a11;

#define LOADB(B0, B1, T) do { \
    B0 = *(const f32x4*)(bgp + (size_t)(T) * 32); \
    B1 = *(const f32x4*)(bgp + (size_t)(T) * 32 + 4); \
  } while (0)
#define LOADA(A0, A1, T) do { \
    A0 = *(const u32x4*)(agp + (size_t)(T) * 32); \
    A1 = *(const u32x4*)(agp + (size_t)(T) * 32 + 8); \
  } while (0)
#define WRITE(B0, B1, A0, A1, BUF) do { \
    nrm += B0[0]*B0[0] + B0[1]*B0[1] + B0[2]*B0[2] + B0[3]*B0[3]; \
    nrm += B1[0]*B1[0] + B1[1]*B1[1] + B1[2]*B1[2] + B1[3]*B1[3]; \
    u32x4 bp; \
    bp.x = cvtpk(B0[0], B0[1]); bp.y = cvtpk(B0[2], B0[3]); \
    bp.z = cvtpk(B1[0], B1[1]); bp.w = cvtpk(B1[2], B1[3]); \
    *(u32x4*)&lsB[BUF][b_ws] = bp; \
    *(u32x4*)&lsA[BUF][a_ws] = A0; \
    *(u32x4*)&lsA[BUF][a_ws + 8] = A1; \
  } while (0)
#define COMPUTE(BUF) do { \
    bf16x8 af[4], bfr[4]; \
    _Pragma("unroll") \
    for (int f = 0; f < 4; ++f) { \
      af[f]  = *(const bf16x8*)&lsA[BUF][(wm + f * 16 + lr) * SROW + lk]; \
      bfr[f] = *(const bf16x8*)&lsB[BUF][(wn + f * 16 + lr) * SROW + lk]; \
    } \
    _Pragma("unroll") \
    for (int i = 0; i < 4; ++i) \
      _Pragma("unroll") \
      for (int j = 0; j < 4; ++j) \
        acc[i][j] = __builtin_amdgcn_mfma_f32_16x16x32_bf16(af[i], bfr[j], acc[i][j], 0, 0, 0); \
  } while (0)

  LOADB(b00, b01, 0); LOADB(b10, b11, 1); LOADB(b20, b21, 2); LOADB(b30, b31, 3);
  LOADA(a00, a01, 0); LOADA(a10, a11, 1);
  WRITE(b00, b01, a00, a01, 0);
  __syncthreads();

  for (int tt = 0; tt < 32; tt += 4) {
    if (tt + 4 < 32) LOADB(b00, b01, tt + 4);
    LOADA(a00, a01, tt + 2);
    COMPUTE(0);
    WRITE(b10, b11, a10, a11, 1);
    __syncthreads();
    if (tt + 5 < 32) LOADB(b10, b11, tt + 5);
    LOADA(a10, a11, tt + 3);
    COMPUTE(1);
    WRITE(b20, b21, a00, a01, 0);
    __syncthreads();
    if (tt + 6 < 32) LOADB(b20, b21, tt + 6);
    if (tt + 4 < 32) LOADA(a00, a01, tt + 4);
    COMPUTE(0);
    WRITE(b30, b31, a10, a11, 1);
    __syncthreads();
    if (tt + 7 < 32) LOADB(b30, b31, tt + 7);
    if (tt + 5 < 32) LOADA(a10, a11, tt + 5);
    COMPUTE(1);
    if (tt + 4 < 32) WRITE(b00, b01, a00, a01, 0);
    __syncthreads();
  }
#undef LOADB
#undef LOADA
#undef WRITE
#undef COMPUTE

  nrm += __shfl_xor(nrm, 1);
  nrm += __shfl_xor(nrm, 2);
  if ((tid & 3) == 0) sm.s.snorm[b_r] = nrm;
  __syncthreads();

#pragma unroll
  for (int j = 0; j < 4; ++j) {
    const int nl = wn + j * 16 + lr;
    const float scl = 1.f / fmaxf(sqrtf(sm.s.snorm[nl]), 1e-8f);
    const size_t ng = (size_t)(n0 + nl);
#pragma unroll
    for (int i = 0; i < 4; ++i) {
      const int mb = wm + i * 16 + l4;
#pragma unroll
      for (int r = 0; r < 4; ++r) {
        sim[(size_t)(mb + r) * NKEYS + ng] = f2bf(acc[i][j][r] * scl);
      }
    }
  }
  __syncthreads();   // all snorm reads done; LDS free for the gemm2 tail

  // ---- gemm2 tail: one 16x32 tile of qt per block (512-tile bijection)
  {
    float (&sA2)[2][32][20] = sm.g.sA2;
    float (&sB2)[2][32][36] = sm.g.sB2;
    const int bm = (int)blockIdx.x >> 5;        // 0..15 (m-tile of 16 rows)
    const int bn2 = (int)blockIdx.x & 31;       // 0..31 (n-tile of 32 cols)
    const int om = tid >> 5;                    // 0..15
    const int on = tid & 31;                    // 0..31
    const int sar = tid >> 5, sak = tid & 31;   // A: 16 rows x 32 k (1 float/thr)
    const int sbr = tid >> 4, sbk = (tid & 15) * 2; // B: 32 rows x 32 k (f32x2/thr)
    const float* ag2 = q  + (size_t)(bm * 16 + sar) * DIM + sak;
    const float* bg2 = Wd + (size_t)(bn2 * 32 + sbr) * DIM + sbk;
    float accq = 0.f;

    sA2[0][sak][sar] = *ag2;
    {
      f32x2 b2 = *(const f32x2*)bg2;
      sB2[0][sbk][sbr] = b2[0];
      sB2[0][sbk + 1][sbr] = b2[1];
    }
    __syncthreads();
    for (int kb = 0; kb < 32; ++kb) {
      const int cur = kb & 1;
      float an = 0.f;
      f32x2 bn_ = {0.f, 0.f};
      if (kb + 1 < 32) {
        an = ag2[(kb + 1) * 32];
        bn_ = *(const f32x2*)(bg2 + (kb + 1) * 32);
      }
#pragma unroll
      for (int kk = 0; kk < 32; ++kk)
        accq += sA2[cur][kk][om] * sB2[cur][kk][on];
      if (kb + 1 < 32) {
        sA2[cur ^ 1][sak][sar] = an;
        sB2[cur ^ 1][sbk][sbr] = bn_[0];
        sB2[cur ^ 1][sbk + 1][sbr] = bn_[1];
      }
      __syncthreads();
    }
    const int gm = bm * 16 + om, gn = bn2 * 32 + on;
    qt[(size_t)gm * DIM + gn] = fmaxf(accq + bd[gn], 0.f);
  }
}

// ---------------- K3: top-64 select + exact fp32 rescore + top-32 + softmax
// attention + LayerNorm + classifier. One block per query row, 512 threads.
// (R4 verbatim)
__global__ __launch_bounds__(512) void select_attn_cls(
    const u16* __restrict__ sim, const float* __restrict__ keys,
    const float* __restrict__ q, const float* __restrict__ qt,
    const float* __restrict__ ln_g, const float* __restrict__ ln_b,
    const float* __restrict__ Wc, const float* __restrict__ bc,
    float* __restrict__ out)
{
  __shared__ int redc[8];
  __shared__ int sc1, sc2;
  __shared__ int clist[NCAND];
  __shared__ float sdq[NCAND], sdqt[NCAND], snr[NCAND];
  __shared__ int srowi[32];
  __shared__ float sw[32];
  __shared__ float red1[8], red2[8];
  __shared__ float smg[2048];
  const int tid = threadIdx.x, lane = tid & 63, wave = tid >> 6;
  const int m = blockIdx.x;

  const u32x4* row = (const u32x4*)(sim + (size_t)m * NKEYS);
  u32 ku[16][4];
#pragma unroll
  for (int i = 0; i < 16; ++i) {
    const u32x4 v = row[i * 512 + tid];
#pragma unroll
    for (int c = 0; c < 4; ++c) {
      u32 lo = v[c] & 0xFFFFu, hi = v[c] >> 16;
      lo ^= (lo & 0x8000u) ? 0xFFFFu : 0x8000u;
      hi ^= (hi & 0x8000u) ? 0xFFFFu : 0x8000u;
      ku[i][c] = lo | (hi << 16);
    }
  }
  int lo_b = 0, hi_b = 65536;
  while (hi_b - lo_b > 1) {
    const u32 mid = (u32)((lo_b + hi_b) >> 1);
    int c = 0;
#pragma unroll
    for (int i = 0; i < 16; ++i)
#pragma unroll
      for (int k = 0; k < 4; ++k) {
        const u32 x = ku[i][k];
        c += ((x & 0xFFFFu) >= mid) ? 1 : 0;
        c += ((x >> 16) >= mid) ? 1 : 0;
      }
#pragma unroll
    for (int j = 32; j; j >>= 1) c += __shfl_xor(c, j);
    if ((tid & 63) == 0) redc[tid >> 6] = c;
    __syncthreads();
    int tot = 0;
#pragma unroll
    for (int w = 0; w < 8; ++w) tot += redc[w];
    if (tot >= NCAND) lo_b = (int)mid; else hi_b = (int)mid;
    __syncthreads();
  }
  const u32 tau = (u32)lo_b;

  int ch = 0;
#pragma unroll
  for (int i = 0; i < 16; ++i)
#pragma unroll
    for (int k = 0; k < 4; ++k) {
      const u32 x = ku[i][k];
      ch += ((x & 0xFFFFu) > tau) ? 1 : 0;
      ch += ((x >> 16) > tau) ? 1 : 0;
    }
#pragma unroll
  for (int j = 32; j; j >>= 1) ch += __shfl_xor(ch, j);
  if ((tid & 63) == 0) redc[tid >> 6] = ch;
  if (tid == 0) { sc1 = 0; sc2 = 0; }
  __syncthreads();
  int nhi = 0;
#pragma unroll
  for (int w = 0; w < 8; ++w) nhi += redc[w];

#pragma unroll
  for (int i = 0; i < 16; ++i)
#pragma unroll
    for (int k = 0; k < 4; ++k) {
      const int nb = (i * 512 + tid) * 8 + k * 2;
      const u32 x = ku[i][k];
      const u32 l = x & 0xFFFFu, h = x >> 16;
      if (l > tau) { int p = atomicAdd(&sc1, 1); clist[p] = nb; }
      else if (l == tau) { int p = atomicAdd(&sc2, 1); if (nhi + p < NCAND) clist[nhi + p] = nb; }
      if (h > tau) { int p = atomicAdd(&sc1, 1); clist[p] = nb + 1; }
      else if (h == tau) { int p = atomicAdd(&sc2, 1); if (nhi + p < NCAND) clist[nhi + p] = nb + 1; }
    }
  __syncthreads();

  f32x4 q4[4], qt4[4];
#pragma unroll
  for (int i = 0; i < 4; ++i) {
    q4[i]  = *(const f32x4*)(q  + (size_t)m * DIM + i * 256 + lane * 4);
    qt4[i] = *(const f32x4*)(qt + (size_t)m * DIM + i * 256 + lane * 4);
  }
  for (int ci = 0; ci < 8; ++ci) {
    const int c = wave * 8 + ci;
    const float* kr = keys + (size_t)clist[c] * DIM;
    float dq = 0.f, dt = 0.f, ss = 0.f;
#pragma unroll
    for (int i = 0; i < 4; ++i) {
      const f32x4 kv = *(const f32x4*)(kr + i * 256 + lane * 4);
#pragma unroll
      for (int e = 0; e < 4; ++e) {
        dq += kv[e] * q4[i][e];
        dt += kv[e] * qt4[i][e];
        ss += kv[e] * kv[e];
      }
    }
#pragma unroll
    for (int j = 32; j; j >>= 1) {
      dq += __shfl_xor(dq, j);
      dt += __shfl_xor(dt, j);
      ss += __shfl_xor(ss, j);
    }
    if (lane == 0) { sdq[c] = dq; sdqt[c] = dt; snr[c] = ss; }
  }
  __syncthreads();

  if (wave == 0) {
    float v = sdq[lane] / fmaxf(sqrtf(snr[lane]), 1e-8f);
    int p = lane;
#pragma unroll
    for (int k = 2; k <= 64; k <<= 1)
#pragma unroll
      for (int j = k >> 1; j > 0; j >>= 1) {
        const float ov = __shfl_xor(v, j);
        const int op = __shfl_xor(p, j);
        const bool tl = ((lane & j) == 0) == ((lane & k) == 0);
        const bool take = tl ? (ov > v) : (ov < v);
        if (take) { v = ov; p = op; }
      }
    float sc = (lane < 32) ? sdqt[p] : -3.4e38f;
    float mx = sc;
#pragma unroll
    for (int j = 16; j; j >>= 1) mx = fmaxf(mx, __shfl_xor(mx, j));
    const float e = (lane < 32) ? expf(sc - mx) : 0.f;
    float s = e;
#pragma unroll
    for (int j = 16; j; j >>= 1) s += __shfl_xor(s, j);
    if (lane < 32) { sw[lane] = e / s; srowi[lane] = clist[p]; }
  }
  __syncthreads();

  const int d0 = tid * 2;
  f32x2 at = {0.f, 0.f};
  for (int j = 0; j < 32; ++j) {
    const float wj = sw[j];
    const f32x2 kv = *(const f32x2*)(keys + (size_t)srowi[j] * DIM + d0);
    at += wj * kv;
  }
  const f32x2 qv = *(const f32x2*)(q + (size_t)m * DIM + d0);
  const f32x2 x = at + qv;
  float s1 = x[0] + x[1];
#pragma unroll
  for (int j = 32; j; j >>= 1) s1 += __shfl_xor(s1, j);
  if (lane == 0) red1[wave] = s1;
  __syncthreads();
  float mu = 0.f;
#pragma unroll
  for (int w = 0; w < 8; ++w) mu += red1[w];
  mu *= (1.f / 1024.f);
  const f32x2 xc = x - mu;
  float s2 = xc[0] * xc[0] + xc[1] * xc[1];
#pragma unroll
  for (int j = 32; j; j >>= 1) s2 += __shfl_xor(s2, j);
  if (lane == 0) red2[wave] = s2;
  __syncthreads();
  float var = 0.f;
#pragma unroll
  for (int w = 0; w < 8; ++w) var += red2[w];
  var *= (1.f / 1024.f);
  const float rstd = rsqrtf(var + 1e-5f);
  const f32x2 g = *(const f32x2*)(ln_g + d0);
  const f32x2 b = *(const f32x2*)(ln_b + d0);
  const f32x2 ma = xc * rstd * g + b;
  *(f32x2*)&smg[d0] = qv;
  *(f32x2*)&smg[1024 + d0] = ma;
  __syncthreads();

  for (int c = wave; c < NCLS; c += 8) {
    const float* w = Wc + (size_t)c * 2048;
    float a = 0.f;
#pragma unroll
    for (int i = 0; i < 8; ++i) {
      const f32x4 wv = *(const f32x4*)(w + i * 256 + lane * 4);
      const f32x4 mv = *(const f32x4*)&smg[i * 256 + lane * 4];
#pragma unroll
      for (int e = 0; e < 4; ++e) a += wv[e] * mv[e];
    }
#pragma unroll
    for (int j = 32; j; j >>= 1) a += __shfl_xor(a, j);
    if (lane == 0) out[(size_t)m * NCLS + c] = a + bc[c];
  }
}

extern "C" void kernel_launch(void* const* d_in, const int* in_sizes, int n_in,
                              void* d_out, int out_size, void* d_ws, size_t ws_size,
                              hipStream_t stream)
{
  const float* query = (const float*)d_in[1];
  const float* keys  = (const float*)d_in[2];
  const float* Wenc  = (const float*)d_in[3];
  const float* benc  = (const float*)d_in[4];
  const float* Wd    = (const float*)d_in[5];
  const float* bd    = (const float*)d_in[6];
  const float* lng   = (const float*)d_in[7];
  const float* lnb   = (const float*)d_in[8];
  const float* Wcls  = (const float*)d_in[9];
  const float* bcls  = (const float*)d_in[10];
  float* out = (float*)d_out;
  char* ws = (char*)d_ws;

  // workspace layout (bytes)
  float* q   = (float*)(ws + 0);              // 1 MB
  u16*   qb  = (u16*)(ws + 1048576u);         // 0.5 MB
  float* qt  = (float*)(ws + 1572864u);       // 1 MB
  u16*   sim = (u16*)(ws + 2621440u);         // 32 MB

  gemm1f<<<dim3(16, 8), 256, 0, stream>>>(query, Wenc, benc, q, qb);
  simgemm2<<<512, 512, 0, stream>>>(keys, qb, q, Wd, bd, sim, qt);
  select_attn_cls<<<256, 512, 0, stream>>>(sim, keys, q, qt, lng, lnb, Wcls, bcls, out);
}